// Round 1
// baseline (749.686 us; speedup 1.0000x reference)
//
#include <hip/hip_runtime.h>
#include <math.h>

#define C_DIM 128
#define SHD   16
#define HID   128
#define MIN_D 64
#define OUT_PER_NODE 2048   // C * (1+3+5+7)
#define CHUNK 16
#define BLK   256
#define SCAN_T 1024

// ---------------- CSR build ----------------

__global__ void zero_counts(int* counts, int n) {
    int i = blockIdx.x * blockDim.x + threadIdx.x;
    if (i < n) counts[i] = 0;
}

__global__ void hist_kernel(const int* __restrict__ dst, int* counts, int E) {
    int i = blockIdx.x * blockDim.x + threadIdx.x;
    if (i < E) atomicAdd(&counts[dst[i]], 1);
}

__global__ __launch_bounds__(SCAN_T)
void scan_kernel(const int* __restrict__ counts, int* row_ptr, int* cursor, int n) {
    const int t = threadIdx.x;
    const int per = (n + SCAN_T - 1) / SCAN_T;   // 10 for n=10000
    int lp[16];
    int base = t * per;
    int sum = 0;
    for (int i = 0; i < per && i < 16; ++i) {
        int idx = base + i;
        int v = (idx < n) ? counts[idx] : 0;
        lp[i] = sum;
        sum += v;
    }
    __shared__ int sbuf[SCAN_T];
    sbuf[t] = sum;
    __syncthreads();
    for (int off = 1; off < SCAN_T; off <<= 1) {
        int v = (t >= off) ? sbuf[t - off] : 0;
        __syncthreads();
        sbuf[t] += v;
        __syncthreads();
    }
    int excl = (t == 0) ? 0 : sbuf[t - 1];
    for (int i = 0; i < per && i < 16; ++i) {
        int idx = base + i;
        if (idx < n) {
            int rp = excl + lp[i];
            row_ptr[idx] = rp;
            cursor[idx]  = rp;
        }
    }
    if (t == SCAN_T - 1) row_ptr[n] = sbuf[SCAN_T - 1];
}

__global__ void scatter_kernel(const int* __restrict__ dst, int* cursor,
                               int* edge_list, int E) {
    int i = blockIdx.x * blockDim.x + threadIdx.x;
    if (i < E) {
        int pos = atomicAdd(&cursor[dst[i]], 1);
        edge_list[pos] = i;
    }
}

// ---------------- fused MLP + tensor-product + segment-sum ----------------
// One block per dst node. 256 threads, each owns 8 of the 2048 outputs.

__global__ __launch_bounds__(BLK)
void mace_main(const float* __restrict__ src_features,
               const float* __restrict__ edge_sh,
               const float* __restrict__ edge_emb,
               const float* __restrict__ W1,
               const float* __restrict__ W2,
               const int*   __restrict__ src,
               const int*   __restrict__ row_ptr,
               const int*   __restrict__ edge_list,
               float* __restrict__ out)
{
    const int n = blockIdx.x;
    const int t = threadIdx.x;
    const float s1 = 0.125f;                 // 1/sqrt(64)
    const float s2 = 0.0883883476483184f;    // 1/sqrt(128)

    __shared__ int   eids[CHUNK];
    __shared__ int   sids[CHUNK];
    __shared__ float tpw[CHUNK][512];        // Phase-B output (aliased for emb staging)
    __shared__ float hbf[CHUNK][HID];
    __shared__ float xsb[CHUNK][C_DIM];
    __shared__ float shb[CHUNK][SHD];
    float (*embb)[MIN_D] = (float (*)[MIN_D])tpw;   // emb dead before tpw written

    // per-thread output mapping: idx = t*8+j -> (l, c, m)
    int lc8[8], c8[8], sh8[8];
#pragma unroll
    for (int j = 0; j < 8; ++j) {
        int idx = t * 8 + j;
        int l, base, shoff;
        if (idx < 128)       { l = 0; base = 0;    shoff = 0; }
        else if (idx < 512)  { l = 1; base = 128;  shoff = 1; }
        else if (idx < 1152) { l = 2; base = 512;  shoff = 4; }
        else                 { l = 3; base = 1152; shoff = 9; }
        int d = 2 * l + 1;
        int r = idx - base;
        int c = r / d;
        int m = r - c * d;
        lc8[j] = l * 128 + c;
        c8[j]  = c;
        sh8[j] = shoff + m;
    }

    float acc[8];
#pragma unroll
    for (int j = 0; j < 8; ++j) acc[j] = 0.f;

    const int rbeg = row_ptr[n];
    const int rend = row_ptr[n + 1];

    for (int cs = rbeg; cs < rend; cs += CHUNK) {
        const int ne = min(CHUNK, rend - cs);

        if (t < ne) {
            int e = edge_list[cs + t];
            eids[t] = e;
            sids[t] = src[e];
        }
        __syncthreads();

        // stage edge_emb, x_src, sh
        for (int i = t; i < ne * MIN_D; i += BLK) {
            int slot = i >> 6, u = i & 63;
            embb[slot][u] = edge_emb[eids[slot] * MIN_D + u];
        }
        for (int i = t; i < ne * C_DIM; i += BLK) {
            int slot = i >> 7, u = i & 127;
            xsb[slot][u] = src_features[sids[slot] * C_DIM + u];
        }
        for (int i = t; i < ne * SHD; i += BLK) {
            int slot = i >> 4, u = i & 15;
            shb[slot][u] = edge_sh[eids[slot] * SHD + u];
        }
        __syncthreads();

        // Phase A: h = silu((emb @ W1) * s1)
        for (int i = t; i < ne * HID; i += BLK) {
            int slot = i >> 7, u = i & 127;
            float z = 0.f;
#pragma unroll 8
            for (int k = 0; k < MIN_D; ++k)
                z += embb[slot][k] * W1[k * HID + u];
            z *= s1;
            float sg = 1.f / (1.f + __expf(-z));
            hbf[slot][u] = z * sg;
        }
        __syncthreads();

        // Phase B: tpw = (h @ W2) * s2  — thread owns columns (2t, 2t+1), all slots
        {
            float a0[CHUNK], a1[CHUNK];
#pragma unroll
            for (int s = 0; s < CHUNK; ++s) { a0[s] = 0.f; a1[s] = 0.f; }
            for (int k = 0; k < HID; ++k) {
                float2 w = *(const float2*)&W2[k * 512 + 2 * t];
#pragma unroll
                for (int s = 0; s < CHUNK; ++s) {
                    float h = hbf[s][k];
                    a0[s] += h * w.x;
                    a1[s] += h * w.y;
                }
            }
#pragma unroll
            for (int s = 0; s < CHUNK; ++s) {
                float2 v; v.x = a0[s] * s2; v.y = a1[s] * s2;
                *(float2*)&tpw[s][2 * t] = v;
            }
        }
        __syncthreads();

        // Phase C: acc[j] += tpw[s][l*128+c] * x_src[s][c] * sh[s][m]
        for (int s = 0; s < ne; ++s) {
#pragma unroll
            for (int j = 0; j < 8; ++j) {
                acc[j] += tpw[s][lc8[j]] * xsb[s][c8[j]] * shb[s][sh8[j]];
            }
        }
        __syncthreads();   // protect LDS before next chunk's staging
    }

    float* op = out + n * OUT_PER_NODE + t * 8;
    *(float4*)(op)     = make_float4(acc[0], acc[1], acc[2], acc[3]);
    *(float4*)(op + 4) = make_float4(acc[4], acc[5], acc[6], acc[7]);
}

// ---------------- launch ----------------

extern "C" void kernel_launch(void* const* d_in, const int* in_sizes, int n_in,
                              void* d_out, int out_size, void* d_ws, size_t ws_size,
                              hipStream_t stream) {
    const float* src_features = (const float*)d_in[0];
    const float* edge_sh      = (const float*)d_in[1];
    const float* edge_emb     = (const float*)d_in[2];
    const float* W1           = (const float*)d_in[3];
    const float* W2           = (const float*)d_in[4];
    const int*   src          = (const int*)d_in[5];
    const int*   dst          = (const int*)d_in[6];

    const int E     = in_sizes[5];
    const int N_DST = out_size / OUT_PER_NODE;

    int* counts    = (int*)d_ws;
    int* row_ptr   = counts  + 16384;
    int* cursor    = row_ptr + 16384;
    int* edge_list = cursor  + 16384;   // E ints

    zero_counts<<<(N_DST + 255) / 256, 256, 0, stream>>>(counts, N_DST);
    hist_kernel<<<(E + 255) / 256, 256, 0, stream>>>(dst, counts, E);
    scan_kernel<<<1, SCAN_T, 0, stream>>>(counts, row_ptr, cursor, N_DST);
    scatter_kernel<<<(E + 255) / 256, 256, 0, stream>>>(dst, cursor, edge_list, E);
    mace_main<<<N_DST, BLK, 0, stream>>>(src_features, edge_sh, edge_emb, W1, W2,
                                         src, row_ptr, edge_list, (float*)d_out);
}

// Round 2
// 515.857 us; speedup vs baseline: 1.4533x; 1.4533x over previous
//
#include <hip/hip_runtime.h>
#include <math.h>

#define C_DIM 128
#define SHD   16
#define HID   128
#define MIN_D 64
#define OUT_PER_NODE 2048   // C * (1+3+5+7)
#define CHUNK 16
#define BLK   256
#define SCAN_T 1024

// LDS row strides (in shorts) — padded, 16B-aligned rows
#define EST 72    // embb stride (64 + 8)
#define HST 136   // hbf stride (128 + 8)
#define TST 520   // tpwb stride (512 + 8)

typedef __attribute__((ext_vector_type(8))) short bf16x8;
typedef __attribute__((ext_vector_type(4))) float f32x4;

__device__ __forceinline__ short f2bf(float x) {
    unsigned u = __builtin_bit_cast(unsigned, x);
    unsigned r = (u + 0x7fffu + ((u >> 16) & 1u)) >> 16;
    return (short)r;
}
__device__ __forceinline__ float bf2f(unsigned h) {
    return __builtin_bit_cast(float, h << 16);
}

// ---------------- CSR build ----------------

__global__ void zero_counts(int* counts, int n) {
    int i = blockIdx.x * blockDim.x + threadIdx.x;
    if (i < n) counts[i] = 0;
}

__global__ void hist_kernel(const int* __restrict__ dst, int* counts, int E) {
    int i = blockIdx.x * blockDim.x + threadIdx.x;
    if (i < E) atomicAdd(&counts[dst[i]], 1);
}

__global__ __launch_bounds__(SCAN_T)
void scan_kernel(const int* __restrict__ counts, int* row_ptr, int* cursor, int n) {
    const int t = threadIdx.x;
    const int per = (n + SCAN_T - 1) / SCAN_T;
    int lp[16];
    int base = t * per;
    int sum = 0;
    for (int i = 0; i < per && i < 16; ++i) {
        int idx = base + i;
        int v = (idx < n) ? counts[idx] : 0;
        lp[i] = sum;
        sum += v;
    }
    __shared__ int sbuf[SCAN_T];
    sbuf[t] = sum;
    __syncthreads();
    for (int off = 1; off < SCAN_T; off <<= 1) {
        int v = (t >= off) ? sbuf[t - off] : 0;
        __syncthreads();
        sbuf[t] += v;
        __syncthreads();
    }
    int excl = (t == 0) ? 0 : sbuf[t - 1];
    for (int i = 0; i < per && i < 16; ++i) {
        int idx = base + i;
        if (idx < n) {
            int rp = excl + lp[i];
            row_ptr[idx] = rp;
            cursor[idx]  = rp;
        }
    }
    if (t == SCAN_T - 1) row_ptr[n] = sbuf[SCAN_T - 1];
}

__global__ void scatter_kernel(const int* __restrict__ dst, int* cursor,
                               int* edge_list, int E) {
    int i = blockIdx.x * blockDim.x + threadIdx.x;
    if (i < E) {
        int pos = atomicAdd(&cursor[dst[i]], 1);
        edge_list[pos] = i;
    }
}

// ---------------- weight conversion (bf16, transposed k-contiguous) ----------------
// w1t[n][k] = bf16(W1[k][n]),  n<128, k<64
__global__ void cvt_w1(const float* __restrict__ W1, short* __restrict__ w1t) {
    int i = blockIdx.x * blockDim.x + threadIdx.x;
    if (i < MIN_D * HID) {
        int k = i / HID, n = i - k * HID;
        w1t[n * MIN_D + k] = f2bf(W1[i]);
    }
}
// w2t[n][k] = bf16(W2[k][n]),  n<512, k<128
__global__ void cvt_w2(const float* __restrict__ W2, short* __restrict__ w2t) {
    int i = blockIdx.x * blockDim.x + threadIdx.x;
    if (i < HID * 512) {
        int k = i / 512, n = i - k * 512;
        w2t[n * HID + k] = f2bf(W2[i]);
    }
}

// ---------------- fused MFMA MLP + tensor-product + segment-sum ----------------
// One block per dst node. 4 waves; wave w owns l = w in Phase C.
// Thread t owns tp_w columns 2t, 2t+1 (both in l = t>>6).

__global__ __launch_bounds__(BLK)
void mace_main(const float* __restrict__ src_features,
               const float* __restrict__ edge_sh,
               const float* __restrict__ edge_emb,
               const short* __restrict__ w1t,
               const short* __restrict__ w2t,
               const int*   __restrict__ src,
               const int*   __restrict__ row_ptr,
               const int*   __restrict__ edge_list,
               float* __restrict__ out)
{
    const int n  = blockIdx.x;
    const int t  = threadIdx.x;
    const int lane = t & 63;
    const int w    = t >> 6;        // wave id == l for Phase C
    const int m16  = lane & 15;     // MFMA M/N lane index
    const int q    = lane >> 4;     // MFMA quad
    const float s2 = 0.0883883476483184f;   // 1/sqrt(128)

    __shared__ __align__(16) short embb[CHUNK * EST];
    __shared__ __align__(16) short hbf [CHUNK * HST];
    __shared__ __align__(16) short tpwb[CHUNK * TST];
    __shared__ __align__(16) float xsb [CHUNK][C_DIM];
    __shared__ float shb[CHUNK][SHD];
    __shared__ int eids[CHUNK];
    __shared__ int sids[CHUNK];

    // Phase-C ownership
    const int col0  = 2 * t;          // tp_w column (0..511), col0>>7 == w
    const int c0    = col0 & 127;     // channel
    const int l     = w;
    const int d     = 2 * l + 1;
    const int shoff = l * l;
    const int obase = 128 * l * l + c0 * d;

    float accA[7], accB[7];
#pragma unroll
    for (int m = 0; m < 7; ++m) { accA[m] = 0.f; accB[m] = 0.f; }

    const int rbeg = row_ptr[n];
    const int rend = row_ptr[n + 1];

    for (int cs = rbeg; cs < rend; cs += CHUNK) {
        const int ne = min(CHUNK, rend - cs);

        if (t < CHUNK && t < ne) {
            int e = edge_list[cs + t];
            eids[t] = e;
            sids[t] = src[e];
        }
        __syncthreads();

        // ---- stage: emb (bf16, zero-padded), x_src (fp32), sh (fp32) ----
        for (int i = t; i < CHUNK * MIN_D; i += BLK) {
            int slot = i >> 6, u = i & 63;
            float v = (slot < ne) ? edge_emb[eids[slot] * MIN_D + u] : 0.f;
            embb[slot * EST + u] = f2bf(v);
        }
        for (int i = t; i < ne * (C_DIM / 4); i += BLK) {
            int slot = i >> 5, u = (i & 31) << 2;
            *(float4*)&xsb[slot][u] =
                *(const float4*)&src_features[sids[slot] * C_DIM + u];
        }
        for (int i = t; i < ne * SHD; i += BLK) {
            int slot = i >> 4, u = i & 15;
            shb[slot][u] = edge_sh[eids[slot] * SHD + u];
        }
        __syncthreads();

        // ---- Phase A: h = silu((emb @ W1)/8), MFMA 16x16x32, N-tiles 2w,2w+1 ----
#pragma unroll
        for (int tile = 0; tile < 2; ++tile) {
            const int nt = w * 2 + tile;
            f32x4 c = {0.f, 0.f, 0.f, 0.f};
#pragma unroll
            for (int ks = 0; ks < 2; ++ks) {
                bf16x8 a = *(const bf16x8*)&embb[m16 * EST + ks * 32 + q * 8];
                bf16x8 b = *(const bf16x8*)&w1t[(nt * 16 + m16) * MIN_D + ks * 32 + q * 8];
                c = __builtin_amdgcn_mfma_f32_16x16x32_bf16(a, b, c, 0, 0, 0);
            }
            const int col = nt * 16 + m16;
#pragma unroll
            for (int r = 0; r < 4; ++r) {
                int row = q * 4 + r;
                float z = c[r] * 0.125f;
                float h = z / (1.f + __expf(-z));
                hbf[row * HST + col] = f2bf(h);
            }
        }
        __syncthreads();

        // ---- Phase B: tp_w = (h @ W2)*s2, MFMA, wave w owns N-tiles 8w..8w+7 ----
        {
            f32x4 acc[8];
#pragma unroll
            for (int j = 0; j < 8; ++j) acc[j] = (f32x4){0.f, 0.f, 0.f, 0.f};
#pragma unroll
            for (int ks = 0; ks < 4; ++ks) {
                bf16x8 a = *(const bf16x8*)&hbf[m16 * HST + ks * 32 + q * 8];
#pragma unroll
                for (int j = 0; j < 8; ++j) {
                    const int nn = (w * 8 + j) * 16 + m16;
                    bf16x8 b = *(const bf16x8*)&w2t[nn * HID + ks * 32 + q * 8];
                    acc[j] = __builtin_amdgcn_mfma_f32_16x16x32_bf16(a, b, acc[j], 0, 0, 0);
                }
            }
#pragma unroll
            for (int j = 0; j < 8; ++j) {
                const int col = (w * 8 + j) * 16 + m16;
#pragma unroll
                for (int r = 0; r < 4; ++r) {
                    int row = q * 4 + r;
                    tpwb[row * TST + col] = f2bf(acc[j][r] * s2);
                }
            }
        }
        __syncthreads();

        // ---- Phase C: acc += tp_w[s][col] * x[s][c] * sh[s][m] ----
        for (int s = 0; s < ne; ++s) {
            float2 x = *(const float2*)&xsb[s][c0];
            unsigned tp2 = *(const unsigned*)&tpwb[s * TST + col0];
            float wx0 = bf2f(tp2 & 0xffffu) * x.x;
            float wx1 = bf2f(tp2 >> 16)     * x.y;
#pragma unroll 7
            for (int m = 0; m < d; ++m) {
                float sh = shb[s][shoff + m];
                accA[m] += wx0 * sh;
                accB[m] += wx1 * sh;
            }
        }
        __syncthreads();   // protect LDS before next chunk staging
    }

    // ---- write: thread owns 2*d contiguous outputs at obase ----
    float* op = out + (size_t)n * OUT_PER_NODE + obase;
#pragma unroll 7
    for (int m = 0; m < d; ++m) op[m] = accA[m];
#pragma unroll 7
    for (int m = 0; m < d; ++m) op[d + m] = accB[m];
}

// ---------------- launch ----------------

extern "C" void kernel_launch(void* const* d_in, const int* in_sizes, int n_in,
                              void* d_out, int out_size, void* d_ws, size_t ws_size,
                              hipStream_t stream) {
    const float* src_features = (const float*)d_in[0];
    const float* edge_sh      = (const float*)d_in[1];
    const float* edge_emb     = (const float*)d_in[2];
    const float* W1           = (const float*)d_in[3];
    const float* W2           = (const float*)d_in[4];
    const int*   src          = (const int*)d_in[5];
    const int*   dst          = (const int*)d_in[6];

    const int E     = in_sizes[5];
    const int N_DST = out_size / OUT_PER_NODE;

    int* counts    = (int*)d_ws;
    int* row_ptr   = counts  + 16384;
    int* cursor    = row_ptr + 16384;
    int* edge_list = cursor  + 16384;           // E ints
    short* w1t     = (short*)(edge_list + E);   // 8192 shorts
    short* w2t     = w1t + MIN_D * HID;         // 65536 shorts

    zero_counts<<<(N_DST + 255) / 256, 256, 0, stream>>>(counts, N_DST);
    hist_kernel<<<(E + 255) / 256, 256, 0, stream>>>(dst, counts, E);
    scan_kernel<<<1, SCAN_T, 0, stream>>>(counts, row_ptr, cursor, N_DST);
    scatter_kernel<<<(E + 255) / 256, 256, 0, stream>>>(dst, cursor, edge_list, E);
    cvt_w1<<<(MIN_D * HID + 255) / 256, 256, 0, stream>>>(W1, w1t);
    cvt_w2<<<(HID * 512 + 255) / 256, 256, 0, stream>>>(W2, w2t);
    mace_main<<<N_DST, BLK, 0, stream>>>(src_features, edge_sh, edge_emb,
                                         w1t, w2t, src, row_ptr, edge_list,
                                         (float*)d_out);
}

// Round 4
// 343.636 us; speedup vs baseline: 2.1816x; 1.5012x over previous
//
#include <hip/hip_runtime.h>
#include <math.h>

#define C_DIM 128
#define SHD   16
#define HID   128
#define MIN_D 64
#define OUT_PER_NODE 2048   // C * (1+3+5+7)
#define BLK   256
#define SCAN_T 1024
#define MT    128           // edges per MLP block

// LDS row strides (shorts), 16B-aligned rows
#define EST 72    // emb stride (64+8)   -> 144 B
#define HST 136   // h   stride (128+8)  -> 272 B

typedef __attribute__((ext_vector_type(8))) short bf16x8;
typedef __attribute__((ext_vector_type(4))) float f32x4;

__device__ __forceinline__ unsigned f2bf_u(float x) {
    unsigned u = __builtin_bit_cast(unsigned, x);
    return (u + 0x7fffu + ((u >> 16) & 1u)) >> 16;   // round-to-nearest-even
}
__device__ __forceinline__ short f2bf(float x) { return (short)f2bf_u(x); }
__device__ __forceinline__ unsigned packbf2(float a, float b) {
    return f2bf_u(a) | (f2bf_u(b) << 16);
}
__device__ __forceinline__ float bf2f(unsigned h) {
    return __builtin_bit_cast(float, h << 16);
}

// ---------------- CSR build ----------------

__global__ void hist_kernel(const int* __restrict__ dst, int* counts, int E) {
    int i = blockIdx.x * blockDim.x + threadIdx.x;
    if (i < E) atomicAdd(&counts[dst[i]], 1);
}

__global__ __launch_bounds__(SCAN_T)
void scan_kernel(const int* __restrict__ counts, int* row_ptr, int* cursor, int n) {
    const int t = threadIdx.x;
    const int per = (n + SCAN_T - 1) / SCAN_T;
    int lp[16];
    int base = t * per;
    int sum = 0;
    for (int i = 0; i < per && i < 16; ++i) {
        int idx = base + i;
        int v = (idx < n) ? counts[idx] : 0;
        lp[i] = sum;
        sum += v;
    }
    __shared__ int sbuf[SCAN_T];
    sbuf[t] = sum;
    __syncthreads();
    for (int off = 1; off < SCAN_T; off <<= 1) {
        int v = (t >= off) ? sbuf[t - off] : 0;
        __syncthreads();
        sbuf[t] += v;
        __syncthreads();
    }
    int excl = (t == 0) ? 0 : sbuf[t - 1];
    for (int i = 0; i < per && i < 16; ++i) {
        int idx = base + i;
        if (idx < n) {
            int rp = excl + lp[i];
            row_ptr[idx] = rp;
            cursor[idx]  = rp;
        }
    }
    if (t == SCAN_T - 1) row_ptr[n] = sbuf[SCAN_T - 1];
}

__global__ void scatter_kernel(const int* __restrict__ dst, const int* __restrict__ src,
                               int* cursor, int* edge_list, int* src_list, int E) {
    int i = blockIdx.x * blockDim.x + threadIdx.x;
    if (i < E) {
        int pos = atomicAdd(&cursor[dst[i]], 1);
        edge_list[pos] = i;
        src_list[pos]  = src[i];
    }
}

// ---------------- weight conversion ----------------
// w1t[n][k] = bf16(W1[k][n] / 8)                        (n<128, k<64)
// w2t[p][k_s] = bf16(W2[ka(k_s)][jcol(p)] / sqrt(128))  (p<512, k_s<128)
//   jcol(p): p = nt*16+m16 -> 32*(nt>>1) + 2*m16 + (nt&1)   [output col interleave]
//   ka(k_s): (2*(k_s>>5) + (k_s&1))*16 + ((k_s>>1)&15)      [h storage interleave]
__global__ void cvt_weights(const float* __restrict__ W1, const float* __restrict__ W2,
                            short* __restrict__ w1t, short* __restrict__ w2t) {
    int i = blockIdx.x * blockDim.x + threadIdx.x;
    if (i < MIN_D * HID) {
        int n = i >> 6, k = i & 63;
        w1t[i] = f2bf(W1[k * HID + n] * 0.125f);
    } else if (i < MIN_D * HID + HID * 512) {
        int j = i - MIN_D * HID;
        int p = j >> 7, ks = j & 127;
        int nt = p >> 4, m16 = p & 15;
        int jcol = 32 * (nt >> 1) + 2 * m16 + (nt & 1);
        int ka   = (2 * (ks >> 5) + (ks & 1)) * 16 + ((ks >> 1) & 15);
        w2t[j] = f2bf(W2[ka * 512 + jcol] * 0.0883883476483184f);
    }
}

// ---------------- kernel 1: edge-parallel fused MLP ----------------
// tp[e][j] (bf16, j = actual W2 column due to folded permutations)
__global__ __launch_bounds__(BLK)
void mlp_kernel(const float* __restrict__ edge_emb,
                const short* __restrict__ w1t,
                const short* __restrict__ w2t,
                unsigned* __restrict__ tp_u,   // E x 256 dwords
                int E)
{
    const int t    = threadIdx.x;
    const int lane = t & 63;
    const int w    = t >> 6;
    const int m16  = lane & 15;
    const int q    = lane >> 4;
    const int e0   = blockIdx.x * MT;

    __shared__ __align__(16) short embb[MT * EST];
    __shared__ __align__(16) short hb  [MT * HST];
    unsigned* embb_u = (unsigned*)embb;
    unsigned* hb_u   = (unsigned*)hb;

    // ---- stage emb (f32 -> bf16), zero-pad tail rows ----
    for (int i = t; i < MT * (MIN_D / 4); i += BLK) {      // 2048 float4 chunks
        int row = i >> 4, c4 = (i & 15) << 2;
        float4 v = make_float4(0.f, 0.f, 0.f, 0.f);
        int ge = e0 + row;
        if (ge < E) v = *(const float4*)&edge_emb[(size_t)ge * MIN_D + c4];
        unsigned lo = packbf2(v.x, v.y), hi = packbf2(v.z, v.w);
        embb_u[row * (EST / 2) + (c4 >> 1)]     = lo;
        embb_u[row * (EST / 2) + (c4 >> 1) + 1] = hi;
    }
    __syncthreads();

    // ---- Phase A: h = silu(emb @ W1/8); wave w owns m-tiles 2w,2w+1 ----
    {
        bf16x8 a[2][2];
#pragma unroll
        for (int mt2 = 0; mt2 < 2; ++mt2) {
            int mt = w * 2 + mt2;
#pragma unroll
            for (int ks = 0; ks < 2; ++ks)
                a[mt2][ks] = *(const bf16x8*)&embb[(mt * 16 + m16) * EST + ks * 32 + q * 8];
        }
#pragma unroll
        for (int u = 0; u < 4; ++u) {
            bf16x8 b0[2], b1[2];
#pragma unroll
            for (int ks = 0; ks < 2; ++ks) {
                b0[ks] = *(const bf16x8*)&w1t[((2 * u) * 16 + m16) * MIN_D + ks * 32 + q * 8];
                b1[ks] = *(const bf16x8*)&w1t[((2 * u + 1) * 16 + m16) * MIN_D + ks * 32 + q * 8];
            }
#pragma unroll
            for (int mt2 = 0; mt2 < 2; ++mt2) {
                int mt = w * 2 + mt2;
                f32x4 c0 = {0.f, 0.f, 0.f, 0.f}, c1 = {0.f, 0.f, 0.f, 0.f};
#pragma unroll
                for (int ks = 0; ks < 2; ++ks) {
                    c0 = __builtin_amdgcn_mfma_f32_16x16x32_bf16(a[mt2][ks], b0[ks], c0, 0, 0, 0);
                    c1 = __builtin_amdgcn_mfma_f32_16x16x32_bf16(a[mt2][ks], b1[ks], c1, 0, 0, 0);
                }
#pragma unroll
                for (int r = 0; r < 4; ++r) {
                    int row = mt * 16 + q * 4 + r;
                    float z0 = c0[r], z1 = c1[r];
                    float h0 = z0 / (1.f + __expf(-z0));
                    float h1 = z1 / (1.f + __expf(-z1));
                    hb_u[row * (HST / 2) + 16 * u + m16] = packbf2(h0, h1);
                }
            }
        }
    }
    __syncthreads();

    // ---- Phase B: tp = h @ W2s; wave w owns m-tiles 2w,2w+1, all 32 n-tiles ----
    {
        bf16x8 a[2][4];
#pragma unroll
        for (int mt2 = 0; mt2 < 2; ++mt2) {
            int mt = w * 2 + mt2;
#pragma unroll
            for (int ks = 0; ks < 4; ++ks)
                a[mt2][ks] = *(const bf16x8*)&hb[(mt * 16 + m16) * HST + ks * 32 + q * 8];
        }
        for (int u = 0; u < 16; ++u) {
            f32x4 c00 = {0.f,0.f,0.f,0.f}, c01 = {0.f,0.f,0.f,0.f};
            f32x4 c10 = {0.f,0.f,0.f,0.f}, c11 = {0.f,0.f,0.f,0.f};
#pragma unroll
            for (int ks = 0; ks < 4; ++ks) {
                bf16x8 b0 = *(const bf16x8*)&w2t[((2 * u) * 16 + m16) * HID + ks * 32 + q * 8];
                bf16x8 b1 = *(const bf16x8*)&w2t[((2 * u + 1) * 16 + m16) * HID + ks * 32 + q * 8];
                c00 = __builtin_amdgcn_mfma_f32_16x16x32_bf16(a[0][ks], b0, c00, 0, 0, 0);
                c01 = __builtin_amdgcn_mfma_f32_16x16x32_bf16(a[0][ks], b1, c01, 0, 0, 0);
                c10 = __builtin_amdgcn_mfma_f32_16x16x32_bf16(a[1][ks], b0, c10, 0, 0, 0);
                c11 = __builtin_amdgcn_mfma_f32_16x16x32_bf16(a[1][ks], b1, c11, 0, 0, 0);
            }
#pragma unroll
            for (int r = 0; r < 4; ++r) {
                int e = e0 + (w * 2) * 16 + q * 4 + r;
                if (e < E) tp_u[(size_t)e * 256 + 16 * u + m16] = packbf2(c00[r], c01[r]);
                int e2 = e + 16;
                if (e2 < E) tp_u[(size_t)e2 * 256 + 16 * u + m16] = packbf2(c10[r], c11[r]);
            }
        }
    }
}

// ---------------- kernel 2: tensor-product + segment-sum ----------------
// One block per dst node; thread t owns tp cols (2t, 2t+1). No LDS, no barriers.
__global__ __launch_bounds__(BLK)
void tp_kernel(const float* __restrict__ src_features,
               const float* __restrict__ edge_sh,
               const unsigned* __restrict__ tp_u,
               const int* __restrict__ row_ptr,
               const int* __restrict__ edge_list,
               const int* __restrict__ src_list,
               float* __restrict__ out)
{
    const int n = blockIdx.x;
    const int t = threadIdx.x;
    const int c0    = (2 * t) & 127;
    const int l     = t >> 6;
    const int d     = 2 * l + 1;
    const int shoff = l * l;
    const int obase = 128 * l * l + c0 * d;

    float accA[7], accB[7];
#pragma unroll
    for (int m = 0; m < 7; ++m) { accA[m] = 0.f; accB[m] = 0.f; }

    const int rbeg = row_ptr[n];
    const int rend = row_ptr[n + 1];

    for (int i = rbeg; i < rend; ++i) {
        int e = edge_list[i];
        int s = src_list[i];
        unsigned tp2 = tp_u[(size_t)e * 256 + t];
        float2 x = *(const float2*)&src_features[(size_t)s * C_DIM + c0];
        float wx0 = bf2f(tp2 & 0xffffu) * x.x;
        float wx1 = bf2f(tp2 >> 16)     * x.y;
        const float* shp = &edge_sh[(size_t)e * SHD + shoff];
#pragma unroll 7
        for (int m = 0; m < d; ++m) {
            float sh = shp[m];
            accA[m] += wx0 * sh;
            accB[m] += wx1 * sh;
        }
    }

    float* op = out + (size_t)n * OUT_PER_NODE + obase;
#pragma unroll 7
    for (int m = 0; m < d; ++m) op[m] = accA[m];
#pragma unroll 7
    for (int m = 0; m < d; ++m) op[d + m] = accB[m];
}

// ---------------- launch ----------------

extern "C" void kernel_launch(void* const* d_in, const int* in_sizes, int n_in,
                              void* d_out, int out_size, void* d_ws, size_t ws_size,
                              hipStream_t stream) {
    const float* src_features = (const float*)d_in[0];
    const float* edge_sh      = (const float*)d_in[1];
    const float* edge_emb     = (const float*)d_in[2];
    const float* W1           = (const float*)d_in[3];
    const float* W2           = (const float*)d_in[4];
    const int*   src          = (const int*)d_in[5];
    const int*   dst          = (const int*)d_in[6];

    const int E     = in_sizes[5];
    const int N_DST = out_size / OUT_PER_NODE;
    const int EB    = (E + MT - 1) / MT;

    // ws layout (16B-aligned pieces first)
    char* p = (char*)d_ws;
    short* w1t      = (short*)p;              p += MIN_D * HID * 2;       // 16 KB
    short* w2t      = (short*)p;              p += HID * 512 * 2;         // 128 KB
    unsigned* tp_u  = (unsigned*)p;           p += (size_t)EB * MT * 1024; // E_pad KB
    int* counts     = (int*)p;                p += 16384 * 4;
    int* row_ptr    = (int*)p;                p += 16384 * 4;
    int* cursor     = (int*)p;                p += 16384 * 4;
    int* edge_list  = (int*)p;                p += (size_t)E * 4;
    int* src_list   = (int*)p;                p += (size_t)E * 4;

    (void)hipMemsetAsync(counts, 0, (size_t)N_DST * 4, stream);
    hist_kernel<<<(E + 255) / 256, 256, 0, stream>>>(dst, counts, E);
    scan_kernel<<<1, SCAN_T, 0, stream>>>(counts, row_ptr, cursor, N_DST);
    scatter_kernel<<<(E + 255) / 256, 256, 0, stream>>>(dst, src, cursor,
                                                        edge_list, src_list, E);
    cvt_weights<<<(MIN_D * HID + HID * 512 + 255) / 256, 256, 0, stream>>>(W1, W2, w1t, w2t);
    mlp_kernel<<<EB, BLK, 0, stream>>>(edge_emb, w1t, w2t, tp_u, E);
    tp_kernel<<<N_DST, BLK, 0, stream>>>(src_features, edge_sh, tp_u,
                                         row_ptr, edge_list, src_list, (float*)d_out);
}

// Round 5
// 266.988 us; speedup vs baseline: 2.8079x; 1.2871x over previous
//
#include <hip/hip_runtime.h>
#include <math.h>

#define C_DIM 128
#define SHD   16
#define HID   128
#define MIN_D 64
#define OUT_PER_NODE 2048   // C * (1+3+5+7)
#define BLK   256
#define SCAN_T 1024
#define MT    128           // edges per MLP block

// LDS row strides (shorts), 16B-aligned rows
#define EST 72    // emb stride (64+8)   -> 144 B
#define HST 136   // h   stride (128+8)  -> 272 B

typedef __attribute__((ext_vector_type(8))) short bf16x8;
typedef __attribute__((ext_vector_type(4))) float f32x4;

__device__ __forceinline__ unsigned f2bf_u(float x) {
    unsigned u = __builtin_bit_cast(unsigned, x);
    return (u + 0x7fffu + ((u >> 16) & 1u)) >> 16;   // round-to-nearest-even
}
__device__ __forceinline__ short f2bf(float x) { return (short)f2bf_u(x); }
__device__ __forceinline__ unsigned packbf2(float a, float b) {
    return f2bf_u(a) | (f2bf_u(b) << 16);
}
__device__ __forceinline__ float bf2f(unsigned h) {
    return __builtin_bit_cast(float, h << 16);
}

// ---------------- prep: histogram + weight conversion (fused) ----------------
// blocks [0, HB): histogram of dst; blocks [HB, HB+CB): weight cvt
__global__ void prep_kernel(const int* __restrict__ dst, int* counts, int E,
                            const float* __restrict__ W1, const float* __restrict__ W2,
                            short* __restrict__ w1t, short* __restrict__ w2t,
                            int HB) {
    int b = blockIdx.x;
    int t = threadIdx.x;
    if (b < HB) {
        int i = b * BLK + t;
        if (i < E) atomicAdd(&counts[dst[i]], 1);
    } else {
        int i = (b - HB) * BLK + t;
        if (i < MIN_D * HID) {
            int n = i >> 6, k = i & 63;
            w1t[i] = f2bf(W1[k * HID + n] * 0.125f);
        } else if (i < MIN_D * HID + HID * 512) {
            int j = i - MIN_D * HID;
            int p = j >> 7, ks = j & 127;
            int nt = p >> 4, m16 = p & 15;
            int jcol = 32 * (nt >> 1) + 2 * m16 + (nt & 1);
            int ka   = (2 * (ks >> 5) + (ks & 1)) * 16 + ((ks >> 1) & 15);
            w2t[j] = f2bf(W2[ka * 512 + jcol] * 0.0883883476483184f);
        }
    }
}

__global__ __launch_bounds__(SCAN_T)
void scan_kernel(const int* __restrict__ counts, int* row_ptr, int* cursor, int n) {
    const int t = threadIdx.x;
    const int per = (n + SCAN_T - 1) / SCAN_T;
    int lp[16];
    int base = t * per;
    int sum = 0;
    for (int i = 0; i < per && i < 16; ++i) {
        int idx = base + i;
        int v = (idx < n) ? counts[idx] : 0;
        lp[i] = sum;
        sum += v;
    }
    __shared__ int sbuf[SCAN_T];
    sbuf[t] = sum;
    __syncthreads();
    for (int off = 1; off < SCAN_T; off <<= 1) {
        int v = (t >= off) ? sbuf[t - off] : 0;
        __syncthreads();
        sbuf[t] += v;
        __syncthreads();
    }
    int excl = (t == 0) ? 0 : sbuf[t - 1];
    for (int i = 0; i < per && i < 16; ++i) {
        int idx = base + i;
        if (idx < n) {
            int rp = excl + lp[i];
            row_ptr[idx] = rp;
            cursor[idx]  = rp;
        }
    }
    if (t == SCAN_T - 1) row_ptr[n] = sbuf[SCAN_T - 1];
}

__global__ void scatter_kernel(const int* __restrict__ dst, const int* __restrict__ src,
                               int* cursor, int2* es_list, int E) {
    int i = blockIdx.x * blockDim.x + threadIdx.x;
    if (i < E) {
        int pos = atomicAdd(&cursor[dst[i]], 1);
        es_list[pos] = make_int2(i, src[i]);
    }
}

// ---------------- kernel 1: edge-parallel fused MLP ----------------
__global__ __launch_bounds__(BLK)
void mlp_kernel(const float* __restrict__ edge_emb,
                const short* __restrict__ w1t,
                const short* __restrict__ w2t,
                unsigned* __restrict__ tp_u,   // E x 256 dwords
                int E)
{
    const int t    = threadIdx.x;
    const int lane = t & 63;
    const int w    = t >> 6;
    const int m16  = lane & 15;
    const int q    = lane >> 4;
    const int e0   = blockIdx.x * MT;

    __shared__ __align__(16) short embb[MT * EST];
    __shared__ __align__(16) short hb  [MT * HST];
    unsigned* embb_u = (unsigned*)embb;
    unsigned* hb_u   = (unsigned*)hb;

    // ---- stage emb (f32 -> bf16), zero-pad tail rows ----
    for (int i = t; i < MT * (MIN_D / 4); i += BLK) {
        int row = i >> 4, c4 = (i & 15) << 2;
        float4 v = make_float4(0.f, 0.f, 0.f, 0.f);
        int ge = e0 + row;
        if (ge < E) v = *(const float4*)&edge_emb[(size_t)ge * MIN_D + c4];
        unsigned lo = packbf2(v.x, v.y), hi = packbf2(v.z, v.w);
        embb_u[row * (EST / 2) + (c4 >> 1)]     = lo;
        embb_u[row * (EST / 2) + (c4 >> 1) + 1] = hi;
    }
    __syncthreads();

    // ---- Phase A: h = silu(emb @ W1/8); wave w owns m-tiles 2w,2w+1 ----
    {
        bf16x8 a[2][2];
#pragma unroll
        for (int mt2 = 0; mt2 < 2; ++mt2) {
            int mt = w * 2 + mt2;
#pragma unroll
            for (int ks = 0; ks < 2; ++ks)
                a[mt2][ks] = *(const bf16x8*)&embb[(mt * 16 + m16) * EST + ks * 32 + q * 8];
        }
#pragma unroll
        for (int u = 0; u < 4; ++u) {
            bf16x8 b0[2], b1[2];
#pragma unroll
            for (int ks = 0; ks < 2; ++ks) {
                b0[ks] = *(const bf16x8*)&w1t[((2 * u) * 16 + m16) * MIN_D + ks * 32 + q * 8];
                b1[ks] = *(const bf16x8*)&w1t[((2 * u + 1) * 16 + m16) * MIN_D + ks * 32 + q * 8];
            }
#pragma unroll
            for (int mt2 = 0; mt2 < 2; ++mt2) {
                int mt = w * 2 + mt2;
                f32x4 c0 = {0.f, 0.f, 0.f, 0.f}, c1 = {0.f, 0.f, 0.f, 0.f};
#pragma unroll
                for (int ks = 0; ks < 2; ++ks) {
                    c0 = __builtin_amdgcn_mfma_f32_16x16x32_bf16(a[mt2][ks], b0[ks], c0, 0, 0, 0);
                    c1 = __builtin_amdgcn_mfma_f32_16x16x32_bf16(a[mt2][ks], b1[ks], c1, 0, 0, 0);
                }
#pragma unroll
                for (int r = 0; r < 4; ++r) {
                    int row = mt * 16 + q * 4 + r;
                    float z0 = c0[r], z1 = c1[r];
                    float h0 = z0 / (1.f + __expf(-z0));
                    float h1 = z1 / (1.f + __expf(-z1));
                    hb_u[row * (HST / 2) + 16 * u + m16] = packbf2(h0, h1);
                }
            }
        }
    }
    __syncthreads();

    // ---- Phase B: tp = h @ W2s; wave w owns m-tiles 2w,2w+1, all 32 n-tiles ----
    {
        bf16x8 a[2][4];
#pragma unroll
        for (int mt2 = 0; mt2 < 2; ++mt2) {
            int mt = w * 2 + mt2;
#pragma unroll
            for (int ks = 0; ks < 4; ++ks)
                a[mt2][ks] = *(const bf16x8*)&hb[(mt * 16 + m16) * HST + ks * 32 + q * 8];
        }
        for (int u = 0; u < 16; ++u) {
            f32x4 c00 = {0.f,0.f,0.f,0.f}, c01 = {0.f,0.f,0.f,0.f};
            f32x4 c10 = {0.f,0.f,0.f,0.f}, c11 = {0.f,0.f,0.f,0.f};
#pragma unroll
            for (int ks = 0; ks < 4; ++ks) {
                bf16x8 b0 = *(const bf16x8*)&w2t[((2 * u) * 16 + m16) * HID + ks * 32 + q * 8];
                bf16x8 b1 = *(const bf16x8*)&w2t[((2 * u + 1) * 16 + m16) * HID + ks * 32 + q * 8];
                c00 = __builtin_amdgcn_mfma_f32_16x16x32_bf16(a[0][ks], b0, c00, 0, 0, 0);
                c01 = __builtin_amdgcn_mfma_f32_16x16x32_bf16(a[0][ks], b1, c01, 0, 0, 0);
                c10 = __builtin_amdgcn_mfma_f32_16x16x32_bf16(a[1][ks], b0, c10, 0, 0, 0);
                c11 = __builtin_amdgcn_mfma_f32_16x16x32_bf16(a[1][ks], b1, c11, 0, 0, 0);
            }
#pragma unroll
            for (int r = 0; r < 4; ++r) {
                int e = e0 + (w * 2) * 16 + q * 4 + r;
                if (e < E) tp_u[(size_t)e * 256 + 16 * u + m16] = packbf2(c00[r], c01[r]);
                int e2 = e + 16;
                if (e2 < E) tp_u[(size_t)e2 * 256 + 16 * u + m16] = packbf2(c10[r], c11[r]);
            }
        }
    }
}

// ---------------- kernel 2: tensor-product + segment-sum ----------------
// One block per dst node; thread t owns tp cols (2t, 2t+1). No LDS, no barriers.
// Templated on L (wave-uniform dispatch) so d is compile-time.

template<int L>
__device__ __forceinline__ void tp_node(
    const float* __restrict__ src_features,
    const float* __restrict__ edge_sh,
    const unsigned* __restrict__ tp_u,
    const int2* __restrict__ es_list,
    float* __restrict__ out,
    int n, int t, int rbeg, int rend)
{
    constexpr int D = 2 * L + 1;
    constexpr int SHOFF = L * L;
    const int c0 = (2 * t) & 127;
    const int obase = 128 * L * L + c0 * D;

    float accA[D], accB[D];
#pragma unroll
    for (int m = 0; m < D; ++m) { accA[m] = 0.f; accB[m] = 0.f; }

    int i = rbeg;
    for (; i + 4 <= rend; i += 4) {
        int2 es[4];
#pragma unroll
        for (int k = 0; k < 4; ++k) es[k] = es_list[i + k];
        unsigned tp2[4]; float2 x[4]; float sh[4][D];
#pragma unroll
        for (int k = 0; k < 4; ++k) {
            tp2[k] = tp_u[(size_t)es[k].x * 256 + t];
            x[k]   = *(const float2*)&src_features[(size_t)es[k].y * C_DIM + c0];
            const float* shp = &edge_sh[(size_t)es[k].x * SHD + SHOFF];
#pragma unroll
            for (int m = 0; m < D; ++m) sh[k][m] = shp[m];
        }
#pragma unroll
        for (int k = 0; k < 4; ++k) {
            float wx0 = bf2f(tp2[k] & 0xffffu) * x[k].x;
            float wx1 = bf2f(tp2[k] >> 16)     * x[k].y;
#pragma unroll
            for (int m = 0; m < D; ++m) {
                accA[m] += wx0 * sh[k][m];
                accB[m] += wx1 * sh[k][m];
            }
        }
    }
    for (; i < rend; ++i) {
        int2 es = es_list[i];
        unsigned tp2 = tp_u[(size_t)es.x * 256 + t];
        float2 x = *(const float2*)&src_features[(size_t)es.y * C_DIM + c0];
        float wx0 = bf2f(tp2 & 0xffffu) * x.x;
        float wx1 = bf2f(tp2 >> 16)     * x.y;
        const float* shp = &edge_sh[(size_t)es.x * SHD + SHOFF];
#pragma unroll
        for (int m = 0; m < D; ++m) {
            float sh = shp[m];
            accA[m] += wx0 * sh;
            accB[m] += wx1 * sh;
        }
    }

    float* op = out + (size_t)n * OUT_PER_NODE + obase;
#pragma unroll
    for (int m = 0; m < D; ++m) op[m] = accA[m];
#pragma unroll
    for (int m = 0; m < D; ++m) op[D + m] = accB[m];
}

__global__ __launch_bounds__(BLK)
void tp_kernel(const float* __restrict__ src_features,
               const float* __restrict__ edge_sh,
               const unsigned* __restrict__ tp_u,
               const int* __restrict__ row_ptr,
               const int2* __restrict__ es_list,
               float* __restrict__ out)
{
    const int n = blockIdx.x;
    const int t = threadIdx.x;
    const int l = t >> 6;       // wave-uniform
    const int rbeg = row_ptr[n];
    const int rend = row_ptr[n + 1];
    if (l == 0)      tp_node<0>(src_features, edge_sh, tp_u, es_list, out, n, t, rbeg, rend);
    else if (l == 1) tp_node<1>(src_features, edge_sh, tp_u, es_list, out, n, t, rbeg, rend);
    else if (l == 2) tp_node<2>(src_features, edge_sh, tp_u, es_list, out, n, t, rbeg, rend);
    else             tp_node<3>(src_features, edge_sh, tp_u, es_list, out, n, t, rbeg, rend);
}

// ---------------- launch ----------------

extern "C" void kernel_launch(void* const* d_in, const int* in_sizes, int n_in,
                              void* d_out, int out_size, void* d_ws, size_t ws_size,
                              hipStream_t stream) {
    const float* src_features = (const float*)d_in[0];
    const float* edge_sh      = (const float*)d_in[1];
    const float* edge_emb     = (const float*)d_in[2];
    const float* W1           = (const float*)d_in[3];
    const float* W2           = (const float*)d_in[4];
    const int*   src          = (const int*)d_in[5];
    const int*   dst          = (const int*)d_in[6];

    const int E     = in_sizes[5];
    const int N_DST = out_size / OUT_PER_NODE;
    const int EB    = (E + MT - 1) / MT;

    // ws layout (16B-aligned pieces first)
    char* p = (char*)d_ws;
    short* w1t      = (short*)p;              p += MIN_D * HID * 2;        // 16 KB
    short* w2t      = (short*)p;              p += HID * 512 * 2;          // 128 KB
    unsigned* tp_u  = (unsigned*)p;           p += (size_t)EB * MT * 1024; // ~100 MB
    int2* es_list   = (int2*)p;               p += (size_t)E * 8;
    int* counts     = (int*)p;                p += 16384 * 4;
    int* row_ptr    = (int*)p;                p += 16384 * 4;
    int* cursor     = (int*)p;                p += 16384 * 4;

    const int HB = (E + BLK - 1) / BLK;
    const int CB = (MIN_D * HID + HID * 512 + BLK - 1) / BLK;

    (void)hipMemsetAsync(counts, 0, (size_t)N_DST * 4, stream);
    prep_kernel<<<HB + CB, BLK, 0, stream>>>(dst, counts, E, W1, W2, w1t, w2t, HB);
    scan_kernel<<<1, SCAN_T, 0, stream>>>(counts, row_ptr, cursor, N_DST);
    scatter_kernel<<<(E + 255) / 256, 256, 0, stream>>>(dst, src, cursor, es_list, E);
    mlp_kernel<<<EB, BLK, 0, stream>>>(edge_emb, w1t, w2t, tp_u, E);
    tp_kernel<<<N_DST, BLK, 0, stream>>>(src_features, edge_sh, tp_u,
                                         row_ptr, es_list, (float*)d_out);
}

// Round 6
// 231.627 us; speedup vs baseline: 3.2366x; 1.1527x over previous
//
#include <hip/hip_runtime.h>
#include <math.h>

#define C_DIM 128
#define SHD   16
#define HID   128
#define MIN_D 64
#define OUT_PER_NODE 2048   // C * (1+3+5+7)
#define BLK   256
#define MBLK  512           // mlp block (8 waves)
#define SCAN_T 1024
#define MT    128           // edges per MLP block

// LDS row stride (shorts), 16B-aligned rows
#define HST 136   // h stride (128+8) -> 272 B

typedef __attribute__((ext_vector_type(8))) short bf16x8;
typedef __attribute__((ext_vector_type(4))) float f32x4;

__device__ __forceinline__ unsigned f2bf_u(float x) {
    unsigned u = __builtin_bit_cast(unsigned, x);
    return (u + 0x7fffu + ((u >> 16) & 1u)) >> 16;   // round-to-nearest-even
}
__device__ __forceinline__ short f2bf(float x) { return (short)f2bf_u(x); }
__device__ __forceinline__ unsigned packbf2(float a, float b) {
    return f2bf_u(a) | (f2bf_u(b) << 16);
}
__device__ __forceinline__ float bf2f(unsigned h) {
    return __builtin_bit_cast(float, h << 16);
}

// ---------------- prep: histogram + weight conversion (fused) ----------------
__global__ void prep_kernel(const int* __restrict__ dst, int* counts, int E,
                            const float* __restrict__ W1, const float* __restrict__ W2,
                            short* __restrict__ w1t, short* __restrict__ w2t,
                            int HB) {
    int b = blockIdx.x;
    int t = threadIdx.x;
    if (b < HB) {
        int i = b * BLK + t;
        if (i < E) atomicAdd(&counts[dst[i]], 1);
    } else {
        int i = (b - HB) * BLK + t;
        if (i < MIN_D * HID) {
            int n = i >> 6, k = i & 63;
            w1t[i] = f2bf(W1[k * HID + n] * 0.125f);
        } else if (i < MIN_D * HID + HID * 512) {
            int j = i - MIN_D * HID;
            int p = j >> 7, ks = j & 127;
            int nt = p >> 4, m16 = p & 15;
            int jcol = 32 * (nt >> 1) + 2 * m16 + (nt & 1);
            int ka   = (2 * (ks >> 5) + (ks & 1)) * 16 + ((ks >> 1) & 15);
            w2t[j] = f2bf(W2[ka * 512 + jcol] * 0.0883883476483184f);
        }
    }
}

__global__ __launch_bounds__(SCAN_T)
void scan_kernel(const int* __restrict__ counts, int* row_ptr, int* cursor, int n) {
    const int t = threadIdx.x;
    const int per = (n + SCAN_T - 1) / SCAN_T;
    int lp[16];
    int base = t * per;
    int sum = 0;
    for (int i = 0; i < per && i < 16; ++i) {
        int idx = base + i;
        int v = (idx < n) ? counts[idx] : 0;
        lp[i] = sum;
        sum += v;
    }
    __shared__ int sbuf[SCAN_T];
    sbuf[t] = sum;
    __syncthreads();
    for (int off = 1; off < SCAN_T; off <<= 1) {
        int v = (t >= off) ? sbuf[t - off] : 0;
        __syncthreads();
        sbuf[t] += v;
        __syncthreads();
    }
    int excl = (t == 0) ? 0 : sbuf[t - 1];
    for (int i = 0; i < per && i < 16; ++i) {
        int idx = base + i;
        if (idx < n) {
            int rp = excl + lp[i];
            row_ptr[idx] = rp;
            cursor[idx]  = rp;
        }
    }
    if (t == SCAN_T - 1) row_ptr[n] = sbuf[SCAN_T - 1];
}

__global__ void scatter_kernel(const int* __restrict__ dst, const int* __restrict__ src,
                               int* cursor, int2* es_list, int E) {
    int i = blockIdx.x * blockDim.x + threadIdx.x;
    if (i < E) {
        int pos = atomicAdd(&cursor[dst[i]], 1);
        es_list[pos] = make_int2(i, src[i]);
    }
}

// ---------------- kernel 1: edge-parallel fused MLP ----------------
// 8 waves. Phase A: wave w computes m-tile w (16 edges) x all 128 h-cols,
// A-frags direct from global. Phase B: wave w owns n-tiles 4w..4w+3 (B in
// registers, loaded pre-barrier), loops all 8 m-tiles from LDS h.
__global__ __launch_bounds__(MBLK)
void mlp_kernel(const float* __restrict__ edge_emb,
                const short* __restrict__ w1t,
                const short* __restrict__ w2t,
                unsigned* __restrict__ tp_u,   // E x 256 dwords
                int E)
{
    const int t    = threadIdx.x;
    const int lane = t & 63;
    const int w    = t >> 6;        // 0..7
    const int m16  = lane & 15;
    const int q    = lane >> 4;
    const int e0   = blockIdx.x * MT;

    __shared__ __align__(16) short hb[MT * HST];
    unsigned* hb_u = (unsigned*)hb;

    union CVT { unsigned u[4]; bf16x8 v; };

    // ---- Phase A: A-frags for m-tile w, direct from global ----
    bf16x8 a[2];
    {
        const int row = e0 + w * 16 + m16;
        if (row < E) {
            const float* rp = &edge_emb[(size_t)row * MIN_D];
#pragma unroll
            for (int ks = 0; ks < 2; ++ks) {
                float4 v0 = *(const float4*)&rp[ks * 32 + q * 8];
                float4 v1 = *(const float4*)&rp[ks * 32 + q * 8 + 4];
                CVT c;
                c.u[0] = packbf2(v0.x, v0.y);
                c.u[1] = packbf2(v0.z, v0.w);
                c.u[2] = packbf2(v1.x, v1.y);
                c.u[3] = packbf2(v1.z, v1.w);
                a[ks] = c.v;
            }
        } else {
            CVT c; c.u[0] = c.u[1] = c.u[2] = c.u[3] = 0u;
            a[0] = c.v; a[1] = c.v;
        }
    }

#pragma unroll
    for (int u2 = 0; u2 < 4; ++u2) {
        f32x4 c0 = {0.f, 0.f, 0.f, 0.f}, c1 = {0.f, 0.f, 0.f, 0.f};
#pragma unroll
        for (int ks = 0; ks < 2; ++ks) {
            bf16x8 b0 = *(const bf16x8*)&w1t[((2 * u2) * 16 + m16) * MIN_D + ks * 32 + q * 8];
            bf16x8 b1 = *(const bf16x8*)&w1t[((2 * u2 + 1) * 16 + m16) * MIN_D + ks * 32 + q * 8];
            c0 = __builtin_amdgcn_mfma_f32_16x16x32_bf16(a[ks], b0, c0, 0, 0, 0);
            c1 = __builtin_amdgcn_mfma_f32_16x16x32_bf16(a[ks], b1, c1, 0, 0, 0);
        }
#pragma unroll
        for (int r = 0; r < 4; ++r) {
            int hrow = w * 16 + q * 4 + r;
            float z0 = c0[r], z1 = c1[r];
            float h0 = z0 / (1.f + __expf(-z0));
            float h1 = z1 / (1.f + __expf(-z1));
            hb_u[hrow * (HST / 2) + 16 * u2 + m16] = packbf2(h0, h1);
        }
    }

    // ---- load Phase-B B-frags BEFORE barrier (overlaps other waves' Phase A) ----
    bf16x8 B[4][4];
#pragma unroll
    for (int j = 0; j < 4; ++j)
#pragma unroll
        for (int ks = 0; ks < 4; ++ks)
            B[j][ks] = *(const bf16x8*)&w2t[((4 * w + j) * 16 + m16) * HID + ks * 32 + q * 8];

    __syncthreads();

    // ---- Phase B: loop all 8 m-tiles; 16 MFMAs each; coalesced pair stores ----
    for (int mt = 0; mt < 8; ++mt) {
        bf16x8 av[4];
#pragma unroll
        for (int ks = 0; ks < 4; ++ks)
            av[ks] = *(const bf16x8*)&hb[(mt * 16 + m16) * HST + ks * 32 + q * 8];
        f32x4 acc[4];
#pragma unroll
        for (int j = 0; j < 4; ++j) acc[j] = (f32x4){0.f, 0.f, 0.f, 0.f};
#pragma unroll
        for (int ks = 0; ks < 4; ++ks)
#pragma unroll
            for (int j = 0; j < 4; ++j)
                acc[j] = __builtin_amdgcn_mfma_f32_16x16x32_bf16(av[ks], B[j][ks], acc[j], 0, 0, 0);
#pragma unroll
        for (int i = 0; i < 2; ++i) {
            const int p = 2 * w + i;
#pragma unroll
            for (int r = 0; r < 4; ++r) {
                int e = e0 + mt * 16 + q * 4 + r;
                if (e < E)
                    tp_u[(size_t)e * 256 + 16 * p + m16] = packbf2(acc[2 * i][r], acc[2 * i + 1][r]);
            }
        }
    }
}

// ---------------- kernel 2: tensor-product + segment-sum ----------------
template<int L>
__device__ __forceinline__ void tp_node(
    const float* __restrict__ src_features,
    const float* __restrict__ edge_sh,
    const unsigned* __restrict__ tp_u,
    const int2* __restrict__ es_list,
    float* __restrict__ out,
    int n, int t, int rbeg, int rend)
{
    constexpr int D = 2 * L + 1;
    constexpr int SHOFF = L * L;
    const int c0 = (2 * t) & 127;
    const int obase = 128 * L * L + c0 * D;

    float accA[D], accB[D];
#pragma unroll
    for (int m = 0; m < D; ++m) { accA[m] = 0.f; accB[m] = 0.f; }

    int i = rbeg;
    for (; i + 4 <= rend; i += 4) {
        int2 es[4];
#pragma unroll
        for (int k = 0; k < 4; ++k) es[k] = es_list[i + k];
        unsigned tp2[4]; float2 x[4]; float sh[4][D];
#pragma unroll
        for (int k = 0; k < 4; ++k) {
            tp2[k] = tp_u[(size_t)es[k].x * 256 + t];
            x[k]   = *(const float2*)&src_features[(size_t)es[k].y * C_DIM + c0];
            const float* shp = &edge_sh[(size_t)es[k].x * SHD + SHOFF];
#pragma unroll
            for (int m = 0; m < D; ++m) sh[k][m] = shp[m];
        }
#pragma unroll
        for (int k = 0; k < 4; ++k) {
            float wx0 = bf2f(tp2[k] & 0xffffu) * x[k].x;
            float wx1 = bf2f(tp2[k] >> 16)     * x[k].y;
#pragma unroll
            for (int m = 0; m < D; ++m) {
                accA[m] += wx0 * sh[k][m];
                accB[m] += wx1 * sh[k][m];
            }
        }
    }
    for (; i < rend; ++i) {
        int2 es = es_list[i];
        unsigned tp2 = tp_u[(size_t)es.x * 256 + t];
        float2 x = *(const float2*)&src_features[(size_t)es.y * C_DIM + c0];
        float wx0 = bf2f(tp2 & 0xffffu) * x.x;
        float wx1 = bf2f(tp2 >> 16)     * x.y;
        const float* shp = &edge_sh[(size_t)es.x * SHD + SHOFF];
#pragma unroll
        for (int m = 0; m < D; ++m) {
            float sh = shp[m];
            accA[m] += wx0 * sh;
            accB[m] += wx1 * sh;
        }
    }

    float* op = out + (size_t)n * OUT_PER_NODE + obase;
#pragma unroll
    for (int m = 0; m < D; ++m) op[m] = accA[m];
#pragma unroll
    for (int m = 0; m < D; ++m) op[D + m] = accB[m];
}

__global__ __launch_bounds__(BLK)
void tp_kernel(const float* __restrict__ src_features,
               const float* __restrict__ edge_sh,
               const unsigned* __restrict__ tp_u,
               const int* __restrict__ row_ptr,
               const int2* __restrict__ es_list,
               float* __restrict__ out)
{
    const int n = blockIdx.x;
    const int t = threadIdx.x;
    const int l = t >> 6;       // wave-uniform
    const int rbeg = row_ptr[n];
    const int rend = row_ptr[n + 1];
    if (l == 0)      tp_node<0>(src_features, edge_sh, tp_u, es_list, out, n, t, rbeg, rend);
    else if (l == 1) tp_node<1>(src_features, edge_sh, tp_u, es_list, out, n, t, rbeg, rend);
    else if (l == 2) tp_node<2>(src_features, edge_sh, tp_u, es_list, out, n, t, rbeg, rend);
    else             tp_node<3>(src_features, edge_sh, tp_u, es_list, out, n, t, rbeg, rend);
}

// ---------------- launch ----------------

extern "C" void kernel_launch(void* const* d_in, const int* in_sizes, int n_in,
                              void* d_out, int out_size, void* d_ws, size_t ws_size,
                              hipStream_t stream) {
    const float* src_features = (const float*)d_in[0];
    const float* edge_sh      = (const float*)d_in[1];
    const float* edge_emb     = (const float*)d_in[2];
    const float* W1           = (const float*)d_in[3];
    const float* W2           = (const float*)d_in[4];
    const int*   src          = (const int*)d_in[5];
    const int*   dst          = (const int*)d_in[6];

    const int E     = in_sizes[5];
    const int N_DST = out_size / OUT_PER_NODE;
    const int EB    = (E + MT - 1) / MT;

    // ws layout (16B-aligned pieces first)
    char* p = (char*)d_ws;
    short* w1t      = (short*)p;              p += MIN_D * HID * 2;        // 16 KB
    short* w2t      = (short*)p;              p += HID * 512 * 2;          // 128 KB
    unsigned* tp_u  = (unsigned*)p;           p += (size_t)EB * MT * 1024; // ~100 MB
    int2* es_list   = (int2*)p;               p += (size_t)E * 8;
    int* counts     = (int*)p;                p += 16384 * 4;
    int* row_ptr    = (int*)p;                p += 16384 * 4;
    int* cursor     = (int*)p;                p += 16384 * 4;

    const int HB = (E + BLK - 1) / BLK;
    const int CB = (MIN_D * HID + HID * 512 + BLK - 1) / BLK;

    (void)hipMemsetAsync(counts, 0, (size_t)N_DST * 4, stream);
    prep_kernel<<<HB + CB, BLK, 0, stream>>>(dst, counts, E, W1, W2, w1t, w2t, HB);
    scan_kernel<<<1, SCAN_T, 0, stream>>>(counts, row_ptr, cursor, N_DST);
    scatter_kernel<<<(E + 255) / 256, 256, 0, stream>>>(dst, src, cursor, es_list, E);
    mlp_kernel<<<EB, MBLK, 0, stream>>>(edge_emb, w1t, w2t, tp_u, E);
    tp_kernel<<<N_DST, BLK, 0, stream>>>(src_features, edge_sh, tp_u,
                                         row_ptr, es_list, (float*)d_out);
}